// Round 4
// baseline (649.017 us; speedup 1.0000x reference)
//
#include <hip/hip_runtime.h>
#include <stdint.h>
#include <stddef.h>

#define D0 4096
#define D1 1024
#define NOUT 1000
#define NB 64
#define NCH0 16          // j-chunks for core 0 (window-synchronized L2 residency)
#define CHSH0 8          // 4096/16 = 256 j per chunk
#define NBK0 (33 * NCH0)

// ---------------------------------------------------------------------------
// Spike pattern for uniform spike coding, N in [0,32] -> 32-bit cycle mask.
// Matches jnp: spacing = 32.f/N (fp32), spike at c iff fmod(c, spacing) < 1.
// floor(c/spacing) < N always true for 0<N<32 (margin >= N/32 >> fp eps).
// ---------------------------------------------------------------------------
__device__ __forceinline__ uint32_t spike_pattern(int N) {
  if (N <= 0) return 0u;
  if (N >= 32) return 0xFFFFFFFFu;
  float spacing = 32.0f / (float)N;
  uint32_t m = 0;
  for (int c = 0; c < 32; ++c) {
    if (fmodf((float)c, spacing) < 1.0f) m |= (1u << c);
  }
  return m;
}

// ---------------------------------------------------------------------------
// Fused prep: [0,64) per-batch counting sort of core-0 inputs by key =
// 33*chunk + N (chunk = j>>8); [64] inverse output index; then w0 / w2
// transposes. Sort blocks first so they overlap the transpose stream.
// Within-bucket order is atomic-nondeterministic: perturbs fp64 bucket sums
// only at ~1e-16, far below threshold-decision margins (absmax stayed 0
// across R1-R3 with the same property).
// ---------------------------------------------------------------------------
__global__ void prep_k(const float* __restrict__ w0, const float* __restrict__ w2,
                       const float* __restrict__ x, const int* __restrict__ idx0,
                       const int* __restrict__ idx_out,
                       float* __restrict__ w0T, float* __restrict__ w2T,
                       uint32_t* __restrict__ perm0, int* __restrict__ starts0,
                       int* __restrict__ inv) {
  int bid = blockIdx.x;
  int tid = threadIdx.x;
  if (bid < NB) {
    __shared__ int keys[D0];
    __shared__ int hist[NBK0];
    __shared__ int base[NBK0 + 1];
    __shared__ int cursor[NBK0];
    int b = bid;
    for (int k = tid; k < NBK0; k += 256) hist[k] = 0;
    __syncthreads();
    for (int j = tid; j < D0; j += 256) {
      int N = (int)rintf(x[(size_t)b * D0 + idx0[j]] * 32.0f);  // round-half-even
      int k = (j >> CHSH0) * 33 + N;
      keys[j] = k;
      atomicAdd(&hist[k], 1);
    }
    __syncthreads();
    if (tid == 0) {
      int s = 0;
      for (int k = 0; k < NBK0; ++k) { base[k] = s; cursor[k] = s; s += hist[k]; }
      base[NBK0] = s;
    }
    __syncthreads();
    for (int k = tid; k <= NBK0; k += 256) starts0[b * (NBK0 + 1) + k] = base[k];
    for (int j = tid; j < D0; j += 256) {
      int pos = atomicAdd(&cursor[keys[j]], 1);
      perm0[(size_t)b * D0 + pos] = (uint32_t)j;
    }
  } else if (bid == NB) {
    for (int o = tid; o < D1; o += 256) inv[o] = -1;
    __syncthreads();
    for (int r = tid; r < NOUT; r += 256) inv[idx_out[r]] = r;
  } else if (bid < NB + 1 + 16384) {
    __shared__ float tile[32][33];
    int tb = bid - (NB + 1);
    int j0 = (tb & 127) * 32;
    int o0 = (tb >> 7) * 32;
    int tx = tid & 31, ty = tid >> 5;
    for (int r = ty; r < 32; r += 8)
      tile[r][tx] = w0[(size_t)(o0 + r) * D0 + j0 + tx];
    __syncthreads();
    for (int r = ty; r < 32; r += 8)
      w0T[(size_t)(j0 + r) * D0 + o0 + tx] = tile[tx][r];
  } else {
    __shared__ float tile2[32][33];
    int tb = bid - (NB + 1 + 16384);
    int j0 = (tb & 31) * 32;
    int o0 = (tb >> 5) * 32;
    int tx = tid & 31, ty = tid >> 5;
    for (int r = ty; r < 32; r += 8) {
      int o = o0 + r;
      tile2[r][tx] = (o < NOUT) ? w2[(size_t)o * D1 + j0 + tx] : 0.0f;
    }
    __syncthreads();
    for (int r = ty; r < 32; r += 8)
      w2T[(size_t)(j0 + r) * D1 + o0 + tx] = tile2[tx][r];
  }
}

// ---------------------------------------------------------------------------
// Core-0 LIF, fp64-exact, no atomics. Thread = one o for batch b. Runs all
// 16 j-chunks in-block, carrying bsum[32] (fp64 per key) across chunks;
// all blocks sweep chunks in the same order, so the instantaneous per-XCD
// wt footprint is ~0.5 MB (L2-resident; only compulsory HBM fetch).
// perm/starts are wave-uniform -> readfirstlane makes addressing scalar
// (SMEM/SALU), leaving only cvt_f64_f32 + add_f64 on the VALU per element.
// Epilogue: pattern-scatter bsum -> contrib (same k-ascending order as R2;
// empty buckets add exact 0.0), then the 32-step membrane scan.
// ---------------------------------------------------------------------------
__launch_bounds__(256, 4)
__global__ void lif0_k(const float* __restrict__ wt, const uint32_t* __restrict__ perm,
                       const int* __restrict__ starts, const float* __restrict__ thr_p,
                       int* __restrict__ cnt_out) {
  __shared__ uint32_t pat[33];
  int tid = threadIdx.x;
  int o = blockIdx.x * 256 + tid;
  int b = blockIdx.y;
  if (tid < 33) pat[tid] = spike_pattern(tid);
  __syncthreads();

  double bsum[32];
#pragma unroll
  for (int k = 0; k < 32; ++k) bsum[k] = 0.0;

  const uint32_t* permb = perm + (size_t)b * D0;
  const int* st = starts + b * (NBK0 + 1);

  for (int ch = 0; ch < NCH0; ++ch) {
    const int* stc = st + ch * 33;
#pragma unroll
    for (int kl = 1; kl <= 32; ++kl) {
      int s = stc[kl], e = stc[kl + 1];
      if (s == e) continue;  // uniform branch
      double a0 = 0.0, a1 = 0.0, a2 = 0.0, a3 = 0.0;
      int i = s;
      for (; i + 4 <= e; i += 4) {
        int j0 = __builtin_amdgcn_readfirstlane((int)permb[i + 0]);
        int j1 = __builtin_amdgcn_readfirstlane((int)permb[i + 1]);
        int j2 = __builtin_amdgcn_readfirstlane((int)permb[i + 2]);
        int j3 = __builtin_amdgcn_readfirstlane((int)permb[i + 3]);
        float f0 = wt[(size_t)j0 * D0 + o];
        float f1 = wt[(size_t)j1 * D0 + o];
        float f2 = wt[(size_t)j2 * D0 + o];
        float f3 = wt[(size_t)j3 * D0 + o];
        a0 += (double)f0; a1 += (double)f1; a2 += (double)f2; a3 += (double)f3;
      }
      for (; i < e; ++i) {
        int j = __builtin_amdgcn_readfirstlane((int)permb[i]);
        a0 += (double)wt[(size_t)j * D0 + o];
      }
      bsum[kl - 1] += (a0 + a1) + (a2 + a3);
    }
  }

  double contrib[32];
#pragma unroll
  for (int t = 0; t < 32; ++t) contrib[t] = 0.0;
#pragma unroll
  for (int k = 1; k <= 32; ++k) {
    uint32_t m = pat[k];
    double v = bsum[k - 1];
#pragma unroll
    for (int t = 0; t < 32; ++t)
      contrib[t] += ((m >> t) & 1u) ? v : 0.0;
  }

  double th = (double)thr_p[0];
  double memb = 0.0;
  int cnt = 0;
#pragma unroll
  for (int t = 0; t < 32; ++t) {
    memb += contrib[t];
    if (memb > th) { memb -= th; ++cnt; }  // strict: threshold < memb
  }
  cnt_out[(size_t)b * D0 + o] = cnt;
}

// ---------------------------------------------------------------------------
// Fused core-2: avg_pool2d on exact spike counts -> N1 = rint(cnt4/4)
// (exact: cnt4 in [0,128]; clip no-op), in-block counting sort (redundantly
// per o-tile, ~µs), LIF over 1024 inputs, and output write via inv index.
// w2T is 4 MB -> L2-resident everywhere.
// ---------------------------------------------------------------------------
__launch_bounds__(256, 4)
__global__ void pool_lif2_k(const int* __restrict__ k0, const int* __restrict__ idx1,
                            const int* __restrict__ idx2, const float* __restrict__ wt,
                            const float* __restrict__ thr_p, const int* __restrict__ inv,
                            float* __restrict__ out) {
  __shared__ int Nls[D1];
  __shared__ int keys[D1];
  __shared__ uint32_t permL[D1];
  __shared__ int hist[33];
  __shared__ int base[34];
  __shared__ int cursor[33];
  __shared__ uint32_t pat[33];
  int b = blockIdx.y;
  int tid = threadIdx.x;
  if (tid < 33) { hist[tid] = 0; pat[tid] = spike_pattern(tid); }
  __syncthreads();
  for (int i = tid; i < D1; i += 256) {
    int c = i >> 4, h2 = (i >> 2) & 3, w2v = i & 3;
    int cnt = 0;
#pragma unroll
    for (int dh = 0; dh < 2; ++dh)
#pragma unroll
      for (int dw = 0; dw < 2; ++dw) {
        int q = c * 64 + (2 * h2 + dh) * 8 + (2 * w2v + dw);
        cnt += k0[(size_t)b * D0 + idx1[q]];
      }
    Nls[i] = (int)rintf((float)cnt * 0.25f);
  }
  __syncthreads();
  for (int j = tid; j < D1; j += 256) {
    int k = Nls[idx2[j]];
    keys[j] = k;
    atomicAdd(&hist[k], 1);
  }
  __syncthreads();
  if (tid == 0) {
    int s = 0;
    for (int k = 0; k < 33; ++k) { base[k] = s; cursor[k] = s; s += hist[k]; }
    base[33] = s;
  }
  __syncthreads();
  for (int j = tid; j < D1; j += 256) {
    int pos = atomicAdd(&cursor[keys[j]], 1);
    permL[pos] = (uint32_t)j;
  }
  __syncthreads();

  int o = blockIdx.x * 256 + tid;
  double bsum[32];
#pragma unroll
  for (int k = 0; k < 32; ++k) bsum[k] = 0.0;
#pragma unroll
  for (int kl = 1; kl <= 32; ++kl) {
    int s = base[kl], e = base[kl + 1];
    if (s == e) continue;
    double a0 = 0.0, a1 = 0.0, a2 = 0.0, a3 = 0.0;
    int i = s;
    for (; i + 4 <= e; i += 4) {
      int j0 = __builtin_amdgcn_readfirstlane((int)permL[i + 0]);
      int j1 = __builtin_amdgcn_readfirstlane((int)permL[i + 1]);
      int j2 = __builtin_amdgcn_readfirstlane((int)permL[i + 2]);
      int j3 = __builtin_amdgcn_readfirstlane((int)permL[i + 3]);
      float f0 = wt[(size_t)j0 * D1 + o];
      float f1 = wt[(size_t)j1 * D1 + o];
      float f2 = wt[(size_t)j2 * D1 + o];
      float f3 = wt[(size_t)j3 * D1 + o];
      a0 += (double)f0; a1 += (double)f1; a2 += (double)f2; a3 += (double)f3;
    }
    for (; i < e; ++i) {
      int j = __builtin_amdgcn_readfirstlane((int)permL[i]);
      a0 += (double)wt[(size_t)j * D1 + o];
    }
    bsum[kl - 1] += (a0 + a1) + (a2 + a3);
  }

  double contrib[32];
#pragma unroll
  for (int t = 0; t < 32; ++t) contrib[t] = 0.0;
#pragma unroll
  for (int k = 1; k <= 32; ++k) {
    uint32_t m = pat[k];
    double v = bsum[k - 1];
#pragma unroll
    for (int t = 0; t < 32; ++t)
      contrib[t] += ((m >> t) & 1u) ? v : 0.0;
  }
  double th = (double)thr_p[0];
  double memb = 0.0;
  int cnt = 0;
#pragma unroll
  for (int t = 0; t < 32; ++t) {
    memb += contrib[t];
    if (memb > th) { memb -= th; ++cnt; }
  }
  int r = inv[o];
  if (r >= 0) out[(size_t)b * NOUT + r] = (float)cnt;
}

// ---------------------------------------------------------------------------
extern "C" void kernel_launch(void* const* d_in, const int* in_sizes, int n_in,
                              void* d_out, int out_size, void* d_ws, size_t ws_size,
                              hipStream_t stream) {
  const float* x      = (const float*)d_in[0];
  const float* w0     = (const float*)d_in[1];
  const float* t0     = (const float*)d_in[2];
  const float* w2     = (const float*)d_in[3];
  const float* t2     = (const float*)d_in[4];
  const int*   idx0   = (const int*)d_in[5];
  const int*   idx1   = (const int*)d_in[6];
  const int*   idx2   = (const int*)d_in[7];
  const int*   idx_out= (const int*)d_in[8];
  float* out = (float*)d_out;

  char* ws = (char*)d_ws;
  float*    w0T     = (float*)ws;    ws += (size_t)D0 * D0 * 4;   // 64 MB
  float*    w2T     = (float*)ws;    ws += (size_t)D1 * D1 * 4;   // 4 MB
  uint32_t* perm0   = (uint32_t*)ws; ws += (size_t)NB * D0 * 4;
  int*      k0      = (int*)ws;      ws += (size_t)NB * D0 * 4;
  int*      starts0 = (int*)ws;      ws += (size_t)NB * (NBK0 + 1) * 4;
  int*      inv     = (int*)ws;      ws += (size_t)D1 * 4;

  prep_k<<<NB + 1 + 16384 + 1024, 256, 0, stream>>>(w0, w2, x, idx0, idx_out,
                                                    w0T, w2T, perm0, starts0, inv);
  lif0_k<<<dim3(D0 / 256, NB), 256, 0, stream>>>(w0T, perm0, starts0, t0, k0);
  pool_lif2_k<<<dim3(D1 / 256, NB), 256, 0, stream>>>(k0, idx1, idx2, w2T, t2, inv, out);
}